// Round 10
// baseline (75.254 us; speedup 1.0000x reference)
//
#include <hip/hip_runtime.h>
#include <stdint.h>
#include <stddef.h>

// BlockLinear: out[b, g*512+n] = sum_m x[b, g*512+m] * blocks[g, m, n]
// G=8, M=N=512, TOKENS=8192. fp32 in/out; compute in bf16 MFMA.
// Round 10: barrier amortization. A staged 8 K-tiles at a time (32 KB,
// single-buffered) -> 4 barriers/block total; inner 8-tile stretch is
// barrier-free {B reg-direct from L2 + ds_read + MFMA}. B uses R9's
// fragment-ready packed layout (never touches LDS). 4 blocks/CU.

typedef __attribute__((ext_vector_type(8))) short sv8;   // 8 x bf16 fragment
typedef __attribute__((ext_vector_type(4))) float fv4;   // 4 x f32 accum

__device__ __forceinline__ uint32_t f2bf(float f) {
    union { float f; uint32_t u; } v; v.f = f;
    uint32_t u = v.u;
    u += 0x7FFFu + ((u >> 16) & 1u);   // RNE
    return u >> 16;
}
__device__ __forceinline__ uint32_t pk2(float a, float b) {
    return f2bf(a) | (f2bf(b) << 16);
}

// bTgl[g][kt] : 2048 units of 16B; unit u = n*4 + c holds
// bf16(blocks[g][kt*32 + c*8 + e][n]), e=0..7.  (fragment-ready layout)
__global__ void bl_pack(const float* __restrict__ blocks,
                        unsigned short* __restrict__ bTgl) {
    __shared__ float tile[64][65];
    const int g  = blockIdx.z;
    const int mt = blockIdx.y;           // 64 m-rows -> kt = mt*2 + {0,1}
    const int n0 = blockIdx.x * 64;
    const float* src = blocks + (size_t)g * 512 * 512;
    const int lane = threadIdx.x & 63;
    const int r0   = threadIdx.x >> 6;   // 0..3
    for (int r = r0; r < 64; r += 4)
        tile[r][lane] = src[(size_t)(mt * 64 + r) * 512 + n0 + lane];
    __syncthreads();
    const int t    = threadIdx.x;        // 0..255
    const int nl   = t >> 2;
    const int c    = t & 3;              // k-chunk == slot
#pragma unroll
    for (int ktl = 0; ktl < 2; ++ktl) {
        const int mb = ktl * 32 + c * 8;
        uint4 w;
        w.x = pk2(tile[mb + 0][nl], tile[mb + 1][nl]);
        w.y = pk2(tile[mb + 2][nl], tile[mb + 3][nl]);
        w.z = pk2(tile[mb + 4][nl], tile[mb + 5][nl]);
        w.w = pk2(tile[mb + 6][nl], tile[mb + 7][nl]);
        const size_t u = ((size_t)(g * 16 + mt * 2 + ktl)) * 2048 + (n0 + nl) * 4 + c;
        *(uint4*)(bTgl + u * 8) = w;
    }
}

// Main GEMM: BM=64, BN=256, 256 threads (4 waves, 1Mx4N),
// wave tile 64x64 = 4x4 fragments of 16x16x32 bf16 MFMA.
// A: LDS [8 tiles][64][32] bf16 (32 KiB), staged per half-K (8 tiles),
// swizzled, shared by 4 waves. B: register loads direct from packed global.
__global__ __launch_bounds__(256, 4) void bl_gemm(
    const float* __restrict__ x,              // [8192][4096]
    const unsigned short* __restrict__ bTgl,  // packed B, see bl_pack
    float* __restrict__ out)                  // [8192][4096]
{
    __shared__ __align__(16) unsigned short As[8][64 * 32];   // 32 KiB

    const int bid = blockIdx.x;
    const int g   = bid & 7;          // group ~ XCD (round-robin dispatch)
    const int rem = bid >> 3;
    const int nt  = rem & 1;
    const int mt  = rem >> 1;         // 0..127

    const int tid  = threadIdx.x;
    const int lane = tid & 63;
    const int w    = tid >> 6;        // 0..3 = wn
    const int lr   = lane & 15;
    const int lg   = lane >> 4;

    fv4 acc[4][4];
#pragma unroll
    for (int i = 0; i < 4; ++i)
#pragma unroll
        for (int j = 0; j < 4; ++j)
            acc[i][j] = (fv4){0.f, 0.f, 0.f, 0.f};

    const float* xg = x + (size_t)(mt * 64) * 4096 + g * 512;

    // ---- A staging: thread -> row arow (0..63), 8-float chunk ac (0..3) ----
    const int arow = tid >> 2;
    const int ac   = tid & 3;
    const float* aSrc = xg + (size_t)arow * 4096 + ac * 8;
    const int aOff = arow * 64 + ((ac ^ ((arow >> 1) & 3)) * 16);  // bytes in tile

    // ---- B fragments: lane-direct from packed layout (R9) ----
    const unsigned short* bLane =
        bTgl + ((size_t)(g * 16) * 2048 +
                (size_t)(nt * 256 + w * 64 + lr) * 4 + lg) * 8;

    // ---- A fragment read slot (bytes) ----
    const int slotOff = (lg ^ ((lr >> 1) & 3)) * 16;

    // Stage 4 K-tiles (batch): 8 float4 loads in flight, then cvt+write.
#define STAGE_QUAD(h, q)                                                   \
    do {                                                                   \
        float4 v_[4][2];                                                   \
        _Pragma("unroll") for (int tt = 0; tt < 4; ++tt) {                 \
            const float* s_ = aSrc + ((h) * 8 + (q) * 4 + tt) * 32;        \
            v_[tt][0] = *(const float4*)s_;                                \
            v_[tt][1] = *(const float4*)(s_ + 4);                          \
        }                                                                  \
        _Pragma("unroll") for (int tt = 0; tt < 4; ++tt) {                 \
            uint4 w_;                                                      \
            w_.x = pk2(v_[tt][0].x, v_[tt][0].y);                          \
            w_.y = pk2(v_[tt][0].z, v_[tt][0].w);                          \
            w_.z = pk2(v_[tt][1].x, v_[tt][1].y);                          \
            w_.w = pk2(v_[tt][1].z, v_[tt][1].w);                          \
            *(uint4*)((char*)&As[(q) * 4 + tt][0] + aOff) = w_;            \
        }                                                                  \
    } while (0)

    // One half-K (8 K-tiles): stage, barrier, barrier-free compute stretch.
#define HALF(h)                                                            \
    do {                                                                   \
        STAGE_QUAD(h, 0);                                                  \
        STAGE_QUAD(h, 1);                                                  \
        __syncthreads();                                                   \
        _Pragma("unroll") for (int k2 = 0; k2 < 8; ++k2) {                 \
            const int kt = (h) * 8 + k2;                                   \
            sv8 b_[4], a_[4];                                              \
            _Pragma("unroll") for (int ni = 0; ni < 4; ++ni)               \
                b_[ni] = *(const sv8*)(bLane + (size_t)kt * 16384 + ni * 512); \
            _Pragma("unroll") for (int mi = 0; mi < 4; ++mi)               \
                a_[mi] = *(const sv8*)((const char*)&As[k2][0] +           \
                                       (mi * 16 + lr) * 64 + slotOff);     \
            __builtin_amdgcn_s_setprio(1);                                 \
            _Pragma("unroll") for (int mi = 0; mi < 4; ++mi)               \
            _Pragma("unroll") for (int ni = 0; ni < 4; ++ni)               \
                acc[mi][ni] = __builtin_amdgcn_mfma_f32_16x16x32_bf16(     \
                    b_[ni], a_[mi], acc[mi][ni], 0, 0, 0);                 \
            __builtin_amdgcn_s_setprio(0);                                 \
        }                                                                  \
    } while (0)

    HALF(0);
    __syncthreads();   // all waves done reading As before restage
    HALF(1);

    // ---- epilogue: nontemporal float4 stores (lane holds 4 consecutive n)
    float* og = out + (size_t)(mt * 64) * 4096 + g * 512 + nt * 256 + w * 64;
#pragma unroll
    for (int mi = 0; mi < 4; ++mi)
#pragma unroll
        for (int ni = 0; ni < 4; ++ni)
            __builtin_nontemporal_store(
                acc[mi][ni],
                (fv4*)(og + (size_t)(mi * 16 + lr) * 4096 + ni * 16 + lg * 4));

#undef STAGE_QUAD
#undef HALF
}

// Safety net if ws is too small for the packed bf16 blocks (4 MiB).
__global__ void bl_fallback(const float* __restrict__ x,
                            const float* __restrict__ blocks,
                            float* __restrict__ out) {
    const int o = blockIdx.x * 256 + threadIdx.x;
    const int col = o & 4095;
    const int row = o >> 12;
    const int g = col >> 9;
    const int n = col & 511;
    const float* xr = x + (size_t)row * 4096 + g * 512;
    const float* wp = blocks + (size_t)g * 512 * 512 + n;
    float s = 0.f;
    for (int m = 0; m < 512; ++m) s += xr[m] * wp[(size_t)m * 512];
    out[o] = s;
}

extern "C" void kernel_launch(void* const* d_in, const int* in_sizes, int n_in,
                              void* d_out, int out_size, void* d_ws, size_t ws_size,
                              hipStream_t stream) {
    const float* x      = (const float*)d_in[0];
    const float* blocks = (const float*)d_in[1];
    float* out          = (float*)d_out;

    const size_t need = (size_t)8 * 16 * 2048 * 16;   // 4 MiB packed B
    if (ws_size >= need) {
        unsigned short* bTgl = (unsigned short*)d_ws;
        bl_pack<<<dim3(8, 8, 8), 256, 0, stream>>>(blocks, bTgl);
        bl_gemm<<<2048, 256, 0, stream>>>(x, bTgl, out);
    } else {
        bl_fallback<<<(8192 * 4096) / 256, 256, 0, stream>>>(x, blocks, out);
    }
}

// Round 11
// 63.412 us; speedup vs baseline: 1.1867x; 1.1867x over previous
//
#include <hip/hip_runtime.h>
#include <stdint.h>
#include <stddef.h>

// BlockLinear: out[b, g*512+n] = sum_m x[b, g*512+m] * blocks[g, m, n]
// G=8, M=N=512, TOKENS=8192. fp32 in/out; compute in bf16 MFMA.
// Round 11: R9 core (B reg-direct from packed L2 panel, A LDS dbuf,
// 4-wave blocks) + LINEAR-STORE EPILOGUE: acc bounced through LDS so
// global stores are 256B-contiguous segments instead of 16x64B scatter.

typedef __attribute__((ext_vector_type(8))) short sv8;   // 8 x bf16 fragment
typedef __attribute__((ext_vector_type(4))) float fv4;   // 4 x f32 accum

__device__ __forceinline__ uint32_t f2bf(float f) {
    union { float f; uint32_t u; } v; v.f = f;
    uint32_t u = v.u;
    u += 0x7FFFu + ((u >> 16) & 1u);   // RNE
    return u >> 16;
}
__device__ __forceinline__ uint32_t pk2(float a, float b) {
    return f2bf(a) | (f2bf(b) << 16);
}

#define BAR()   __builtin_amdgcn_s_barrier()
#define SB0()   __builtin_amdgcn_sched_barrier(0)
#define LGKM0() do { asm volatile("s_waitcnt lgkmcnt(0)" ::: "memory"); SB0(); } while (0)

// bTgl[g][kt] : 2048 units of 16B; unit u = n*4 + c holds
// bf16(blocks[g][kt*32 + c*8 + e][n]), e=0..7.  (fragment-ready layout)
__global__ void bl_pack(const float* __restrict__ blocks,
                        unsigned short* __restrict__ bTgl) {
    __shared__ float tile[64][65];
    const int g  = blockIdx.z;
    const int mt = blockIdx.y;           // 64 m-rows -> kt = mt*2 + {0,1}
    const int n0 = blockIdx.x * 64;
    const float* src = blocks + (size_t)g * 512 * 512;
    const int lane = threadIdx.x & 63;
    const int r0   = threadIdx.x >> 6;   // 0..3
    for (int r = r0; r < 64; r += 4)
        tile[r][lane] = src[(size_t)(mt * 64 + r) * 512 + n0 + lane];
    __syncthreads();
    const int t    = threadIdx.x;        // 0..255
    const int nl   = t >> 2;
    const int c    = t & 3;              // k-chunk == slot (no swizzle)
#pragma unroll
    for (int ktl = 0; ktl < 2; ++ktl) {
        const int mb = ktl * 32 + c * 8;
        uint4 w;
        w.x = pk2(tile[mb + 0][nl], tile[mb + 1][nl]);
        w.y = pk2(tile[mb + 2][nl], tile[mb + 3][nl]);
        w.z = pk2(tile[mb + 4][nl], tile[mb + 5][nl]);
        w.w = pk2(tile[mb + 6][nl], tile[mb + 7][nl]);
        const size_t u = ((size_t)(g * 16 + mt * 2 + ktl)) * 2048 + (n0 + nl) * 4 + c;
        *(uint4*)(bTgl + u * 8) = w;
    }
}

// Main GEMM: BM=64, BN=256, BK=32, 256 threads (4 waves, 1Mx4N),
// wave tile 64x64 = 4x4 fragments of 16x16x32 bf16 MFMA.
// A: LDS dbuf (8 KiB), swizzled. B: register prefetch direct from packed
// global (no LDS). Epilogue: LDS bounce -> 256B-linear stores.
__global__ __launch_bounds__(256, 4) void bl_gemm(
    const float* __restrict__ x,              // [8192][4096]
    const unsigned short* __restrict__ bTgl,  // packed B, see bl_pack
    float* __restrict__ out)                  // [8192][4096]
{
    __shared__ __align__(16) unsigned short As[2][64 * 32];    // 8 KiB
    __shared__ __align__(16) float epi[16][264];               // 16.5 KiB

    const int bid = blockIdx.x;
    const int g   = bid & 7;          // group ~ XCD (round-robin dispatch)
    const int rem = bid >> 3;
    const int nt  = rem & 1;
    const int mt  = rem >> 1;         // 0..127

    const int tid  = threadIdx.x;
    const int lane = tid & 63;
    const int w    = tid >> 6;        // 0..3 = wn
    const int lr   = lane & 15;
    const int lg   = lane >> 4;

    fv4 acc[4][4];
#pragma unroll
    for (int i = 0; i < 4; ++i)
#pragma unroll
        for (int j = 0; j < 4; ++j)
            acc[i][j] = (fv4){0.f, 0.f, 0.f, 0.f};

    const float* xg = x + (size_t)(mt * 64) * 4096 + g * 512;

    // ---- A staging: thread -> row arow (0..63), 8-float chunk ac (0..3) ----
    const int arow = tid >> 2;
    const int ac   = tid & 3;
    const float* aSrc = xg + (size_t)arow * 4096 + ac * 8;
    const int aOff = arow * 64 + ((ac ^ ((arow >> 1) & 3)) * 16);  // bytes

    // ---- B fragments: lane-direct from packed layout ----
    const unsigned short* bLane =
        bTgl + ((size_t)(g * 16) * 2048 +
                (size_t)(nt * 256 + w * 64 + lr) * 4 + lg) * 8;

    // ---- A fragment read slot (bytes) ----
    const int slotOff = (lg ^ ((lr >> 1) & 3)) * 16;

    float4 a0_, a1_;       // in-flight A (8 floats)
    sv8 bP[4], bQ[4];      // B fragments: current / next tile

#define ISSUE_A(kt)                                                        \
    do {                                                                   \
        const float* s_ = aSrc + (kt) * 32;                                \
        a0_ = *(const float4*)s_;                                          \
        a1_ = *(const float4*)(s_ + 4);                                    \
    } while (0)

#define ISSUE_BF(kt, dst)                                                  \
    do { _Pragma("unroll") for (int ni = 0; ni < 4; ++ni)                  \
        dst[ni] = *(const sv8*)(bLane + (size_t)(kt) * 16384 + ni * 512);  \
    } while (0)

#define WRITE_A(bufw)                                                      \
    do {                                                                   \
        uint4 w_;                                                          \
        w_.x = pk2(a0_.x, a0_.y); w_.y = pk2(a0_.z, a0_.w);                \
        w_.z = pk2(a1_.x, a1_.y); w_.w = pk2(a1_.z, a1_.w);                \
        *(uint4*)((char*)&As[0][0] + (bufw) * 4096 + aOff) = w_;           \
    } while (0)

#define COMPUTE(rb, breg)                                                  \
    do {                                                                   \
        sv8 a_[4];                                                         \
        _Pragma("unroll") for (int mi = 0; mi < 4; ++mi)                   \
            a_[mi] = *(const sv8*)((const char*)&As[0][0] + (rb) * 4096 +  \
                                   (mi * 16 + lr) * 64 + slotOff);         \
        __builtin_amdgcn_s_setprio(1);                                     \
        _Pragma("unroll") for (int mi = 0; mi < 4; ++mi)                   \
        _Pragma("unroll") for (int ni = 0; ni < 4; ++ni)                   \
            acc[mi][ni] = __builtin_amdgcn_mfma_f32_16x16x32_bf16(         \
                breg[ni], a_[mi], acc[mi][ni], 0, 0, 0);                   \
        __builtin_amdgcn_s_setprio(0);                                     \
    } while (0)

    // ---- prologue: tile 0 -> buf0 + bP ----
    ISSUE_BF(0, bP);
    ISSUE_A(0);
    WRITE_A(0);
    LGKM0();
    BAR();

#pragma unroll 1
    for (int kt = 0; kt < 16; kt += 2) {
        const int ka = kt + 1 < 16 ? kt + 1 : 15;
        const int kb = kt + 2 < 16 ? kt + 2 : 15;
        // phase A: tile kt (buf0, bP); stage kt+1
        ISSUE_BF(ka, bQ);
        ISSUE_A(ka);
        COMPUTE(0, bP);
        WRITE_A(1);
        LGKM0();
        BAR();
        // phase B: tile kt+1 (buf1, bQ); stage kt+2
        ISSUE_BF(kb, bP);
        ISSUE_A(kb);
        COMPUTE(1, bQ);
        WRITE_A(0);
        LGKM0();
        BAR();
    }

    // ---- epilogue: LDS bounce -> linear 256B-segment stores ----
    // out block strip: rows mt*64 .. +64, cols g*512 + nt*256 .. +256
    float* og = out + (size_t)(mt * 64) * 4096 + g * 512 + nt * 256;
    const int er  = tid >> 4;     // 0..15 row within round
    const int ec  = tid & 15;     // 16B unit within 256B chunk
#pragma unroll
    for (int mi = 0; mi < 4; ++mi) {
        // deposit: wave w fills cols [w*64, w*64+64) of rows lr
#pragma unroll
        for (int ni = 0; ni < 4; ++ni) {
            float4 v;
            v.x = acc[mi][ni][0]; v.y = acc[mi][ni][1];
            v.z = acc[mi][ni][2]; v.w = acc[mi][ni][3];
            *(float4*)&epi[lr][w * 64 + ni * 16 + lg * 4] = v;
        }
        __syncthreads();
        // drain: 256 threads, each row (er) covered by 16 threads (ec),
        // 4 passes cover 256 cols; stores are 256B-contiguous per 16 lanes.
#pragma unroll
        for (int pass = 0; pass < 4; ++pass) {
            const int col = (ec + pass * 16) * 4;
            float4 v = *(float4*)&epi[er][col];
            fv4 vv; vv[0] = v.x; vv[1] = v.y; vv[2] = v.z; vv[3] = v.w;
            __builtin_nontemporal_store(
                vv, (fv4*)(og + (size_t)(mi * 16 + er) * 4096 + col));
        }
        __syncthreads();
    }

#undef ISSUE_A
#undef ISSUE_BF
#undef WRITE_A
#undef COMPUTE
}

// Safety net if ws is too small for the packed bf16 blocks (4 MiB).
__global__ void bl_fallback(const float* __restrict__ x,
                            const float* __restrict__ blocks,
                            float* __restrict__ out) {
    const int o = blockIdx.x * 256 + threadIdx.x;
    const int col = o & 4095;
    const int row = o >> 12;
    const int g = col >> 9;
    const int n = col & 511;
    const float* xr = x + (size_t)row * 4096 + g * 512;
    const float* wp = blocks + (size_t)g * 512 * 512 + n;
    float s = 0.f;
    for (int m = 0; m < 512; ++m) s += xr[m] * wp[(size_t)m * 512];
    out[o] = s;
}

extern "C" void kernel_launch(void* const* d_in, const int* in_sizes, int n_in,
                              void* d_out, int out_size, void* d_ws, size_t ws_size,
                              hipStream_t stream) {
    const float* x      = (const float*)d_in[0];
    const float* blocks = (const float*)d_in[1];
    float* out          = (float*)d_out;

    const size_t need = (size_t)8 * 16 * 2048 * 16;   // 4 MiB packed B
    if (ws_size >= need) {
        unsigned short* bTgl = (unsigned short*)d_ws;
        bl_pack<<<dim3(8, 8, 8), 256, 0, stream>>>(blocks, bTgl);
        bl_gemm<<<2048, 256, 0, stream>>>(x, bTgl, out);
    } else {
        bl_fallback<<<(8192 * 4096) / 256, 256, 0, stream>>>(x, blocks, out);
    }
}